// Round 3
// baseline (224.121 us; speedup 1.0000x reference)
//
#include <hip/hip_runtime.h>

#define NB 8192
#define NS 50
#define ND 128
#define NP 16
#define NU 50000
#define NRED 64   // stage-1 reduction blocks for shared-proto mean

// ---------------- inverse map ----------------
__global__ void k_init_map(int* __restrict__ map) {
    int i = blockIdx.x * blockDim.x + threadIdx.x;
    if (i < NU) map[i] = -1;
}

__global__ void k_scatter_map(const int* __restrict__ user_idx, int* __restrict__ map) {
    int b = blockIdx.x * blockDim.x + threadIdx.x;
    if (b < NB) map[user_idx[b]] = b;
}

// ---------------- fused main kernel ----------------
// one 256-thread block per user row u.
//  unmapped: copy 16x128 row, out_ic = ic
//  mapped b: compute upd[b] (masked mean over S, l2-normalize) with float4
//            feature loads, write upd to ws, blend row from LDS, out_ic = ic+1
__global__ __launch_bounds__(256) void k_big(
    const float* __restrict__ proto,
    const float* __restrict__ ic,
    const float* __restrict__ features,
    const float* __restrict__ mask,
    const int* __restrict__ map,
    float* __restrict__ out_proto,
    float* __restrict__ out_ic,
    float* __restrict__ upd)
{
    int u = blockIdx.x;
    int t = threadIdx.x;
    int b = map[u];

    const float4* proto4 = (const float4*)proto;
    float4* out4 = (float4*)out_proto;
    size_t base = (size_t)u * (NP * ND / 4);   // 512 float4 per row

    if (b < 0) {
        // pure copy row (uniform branch per block)
        out4[base + t]       = proto4[base + t];
        out4[base + t + 256] = proto4[base + t + 256];
        if (t == 0) out_ic[u] = ic[u];
        return;
    }

    __shared__ float  smask[NS];
    __shared__ float4 part[8][32];
    __shared__ float4 updv[32];

    if (t < NS) smask[t] = mask[(size_t)b * NS + t];
    __syncthreads();

    // masked accumulation: thread t -> float4 column q = t&31, s-group g = t>>5
    int q = t & 31;
    int g = t >> 5;
    const float4* f4 = (const float4*)features + (size_t)b * (NS * ND / 4);
    float4 acc = {0.f, 0.f, 0.f, 0.f};
    for (int s = g; s < NS; s += 8) {
        float w = smask[s];
        float4 v = f4[s * 32 + q];
        acc.x += v.x * w; acc.y += v.y * w; acc.z += v.z * w; acc.w += v.w * w;
    }
    part[g][q] = acc;
    __syncthreads();

    if (t < 32) {
        float msum = 0.f;
#pragma unroll
        for (int s = 0; s < NS; ++s) msum += smask[s];

        float4 a = part[0][t];
#pragma unroll
        for (int g2 = 1; g2 < 8; ++g2) {
            float4 p = part[g2][t];
            a.x += p.x; a.y += p.y; a.z += p.z; a.w += p.w;
        }
        float invm = 1.0f / fmaxf(msum, 1e-6f);
        a.x *= invm; a.y *= invm; a.z *= invm; a.w *= invm;

        // L2 norm across 128 dims (32 lanes x 4)
        float d2 = a.x * a.x + a.y * a.y + a.z * a.z + a.w * a.w;
#pragma unroll
        for (int mm = 16; mm >= 1; mm >>= 1) d2 += __shfl_xor(d2, mm, 64);
        float inv = 1.0f / fmaxf(sqrtf(d2), 1e-12f);
        a.x *= inv; a.y *= inv; a.z *= inv; a.w *= inv;

        updv[t] = a;
        ((float4*)upd)[(size_t)b * 32 + t] = a;   // for shared-proto mean
    }
    __syncthreads();

    float icv = ic[u];
    float m = fminf(fmaxf(0.9f + icv * 0.001f, 0.9f), 0.99f);
    float om = 1.0f - m;
    if (t == 0) out_ic[u] = icv + 1.0f;

#pragma unroll
    for (int rep = 0; rep < 2; ++rep) {
        int idx = t + rep * 256;
        float4 v = proto4[base + idx];
        float4 uu = updv[idx & 31];
        v.x = m * v.x + om * uu.x;
        v.y = m * v.y + om * uu.y;
        v.z = m * v.z + om * uu.z;
        v.w = m * v.w + om * uu.w;
        out4[base + idx] = v;
    }
}

// ---------------- stage-1 column sum over B ----------------
__global__ void k_colsum(const float* __restrict__ upd, float* __restrict__ part) {
    int blk = blockIdx.x;
    int t = threadIdx.x;
    int d = t & 127;
    int h = t >> 7;

    const int rows = NB / NRED;          // 128
    int r0 = blk * rows;

    float s = 0.f;
    for (int r = r0 + h; r < r0 + rows; r += 2)
        s += upd[(size_t)r * ND + d];

    __shared__ float red[2][ND];
    red[h][d] = s;
    __syncthreads();
    if (h == 0)
        part[(size_t)blk * ND + d] = red[0][d] + red[1][d];
}

// ---------------- stage-2: mean, normalize, blend shared ----------------
__global__ void k_shared_final(const float* __restrict__ part,
                               const float* __restrict__ shared_in,
                               float* __restrict__ shared_out) {
    int d = threadIdx.x;   // 0..127

    float tot = 0.f;
#pragma unroll
    for (int j = 0; j < NRED; ++j) tot += part[(size_t)j * ND + d];
    float mean = tot / (float)NB;

    __shared__ float red[ND];
    red[d] = mean * mean;
    __syncthreads();
    for (int off = 64; off > 0; off >>= 1) {
        if (d < off) red[d] += red[d + off];
        __syncthreads();
    }
    float inv = 1.0f / fmaxf(sqrtf(red[0]), 1e-12f);
    float su = mean * inv;

#pragma unroll
    for (int p = 0; p < NP; ++p)
        shared_out[p * ND + d] = 0.9f * shared_in[p * ND + d] + 0.1f * su;
}

extern "C" void kernel_launch(void* const* d_in, const int* in_sizes, int n_in,
                              void* d_out, int out_size, void* d_ws, size_t ws_size,
                              hipStream_t stream) {
    const float* user_prototypes   = (const float*)d_in[0];  // [NU, NP, ND]
    const float* shared_prototypes = (const float*)d_in[1];  // [1, NP, ND]
    const float* interaction_count = (const float*)d_in[2];  // [NU]
    const float* features          = (const float*)d_in[3];  // [NB, NS, ND]
    const float* success_mask      = (const float*)d_in[4];  // [NB, NS]
    const int*   user_idx          = (const int*)d_in[5];    // [NB]

    float* out_proto  = (float*)d_out;                         // NU*NP*ND
    float* out_shared = out_proto + (size_t)NU * NP * ND;      // NP*ND
    float* out_ic     = out_shared + NP * ND;                  // NU

    // workspace layout (16B aligned chunks)
    int*   map  = (int*)d_ws;                                  // NU ints (200 KB)
    float* upd  = (float*)((char*)d_ws + 200704);              // NB*ND floats (4 MB)
    float* part = upd + (size_t)NB * ND;                       // NRED*ND floats (32 KB)

    k_init_map<<<(NU + 255) / 256, 256, 0, stream>>>(map);
    k_scatter_map<<<(NB + 255) / 256, 256, 0, stream>>>(user_idx, map);

    k_big<<<NU, 256, 0, stream>>>(user_prototypes, interaction_count,
                                  features, success_mask, map,
                                  out_proto, out_ic, upd);

    k_colsum<<<NRED, 256, 0, stream>>>(upd, part);
    k_shared_final<<<1, ND, 0, stream>>>(part, shared_prototypes, out_shared);
}

// Round 4
// 189.800 us; speedup vs baseline: 1.1808x; 1.1808x over previous
//
#include <hip/hip_runtime.h>

#define NB 8192
#define NS 50
#define ND 128
#define NP 16
#define NU 50000
#define NRED 128   // stage-1 reduction blocks for shared-proto mean

typedef float f4v __attribute__((ext_vector_type(4)));

// ---------------- scatter map (no init needed: entries validated on read) ----
__global__ void k_scatter_map(const int* __restrict__ user_idx, int* __restrict__ map) {
    int b = blockIdx.x * blockDim.x + threadIdx.x;
    if (b < NB) map[user_idx[b]] = b;
}

// ---------------- fused main kernel ----------------
// one 256-thread block per user row u.
// map validation: entry b is live iff 0<=b<NB and user_idx[b]==u. This is
// correct for ANY prior ws content (poison or stale writes from a previous
// identical call), so no init pass is needed.
__global__ __launch_bounds__(256) void k_big(
    const float* __restrict__ proto,
    const float* __restrict__ ic,
    const float* __restrict__ features,
    const float* __restrict__ mask,
    const int* __restrict__ map,
    const int* __restrict__ user_idx,
    float* __restrict__ out_proto,
    float* __restrict__ out_ic,
    float* __restrict__ upd)
{
    int u = blockIdx.x;
    int t = threadIdx.x;

    int b = map[u];
    bool mapped = (b >= 0) && (b < NB);
    if (mapped) mapped = (user_idx[b] == u);

    const f4v* proto4 = (const f4v*)proto;
    f4v* out4 = (f4v*)out_proto;
    size_t base = (size_t)u * (NP * ND / 4);   // 512 float4 per row

    if (!mapped) {
        // pure streaming copy row, bypass caches
        f4v v0 = __builtin_nontemporal_load(&proto4[base + t]);
        f4v v1 = __builtin_nontemporal_load(&proto4[base + t + 256]);
        __builtin_nontemporal_store(v0, &out4[base + t]);
        __builtin_nontemporal_store(v1, &out4[base + t + 256]);
        if (t == 0) out_ic[u] = ic[u];
        return;
    }

    __shared__ float smask[NS];
    __shared__ f4v   part[8][32];
    __shared__ f4v   updv[32];

    if (t < NS) smask[t] = mask[(size_t)b * NS + t];
    __syncthreads();

    // masked accumulation: thread t -> float4 column q = t&31, s-group g = t>>5
    int q = t & 31;
    int g = t >> 5;
    const f4v* f4 = (const f4v*)features + (size_t)b * (NS * ND / 4);
    f4v acc = {0.f, 0.f, 0.f, 0.f};
    for (int s = g; s < NS; s += 8) {
        float w = smask[s];
        f4v v = __builtin_nontemporal_load(&f4[s * 32 + q]);
        acc += v * w;
    }
    part[g][q] = acc;
    __syncthreads();

    if (t < 32) {
        float msum = 0.f;
#pragma unroll
        for (int s = 0; s < NS; ++s) msum += smask[s];

        f4v a = part[0][t];
#pragma unroll
        for (int g2 = 1; g2 < 8; ++g2) a += part[g2][t];

        a *= (1.0f / fmaxf(msum, 1e-6f));

        // L2 norm across 128 dims (32 lanes x 4)
        float d2 = a.x * a.x + a.y * a.y + a.z * a.z + a.w * a.w;
#pragma unroll
        for (int mm = 16; mm >= 1; mm >>= 1) d2 += __shfl_xor(d2, mm, 64);
        a *= (1.0f / fmaxf(sqrtf(d2), 1e-12f));

        updv[t] = a;
        ((f4v*)upd)[(size_t)b * 32 + t] = a;   // cached: consumed by k_colsum
    }
    __syncthreads();

    float icv = ic[u];
    float m = fminf(fmaxf(0.9f + icv * 0.001f, 0.9f), 0.99f);
    float om = 1.0f - m;
    if (t == 0) out_ic[u] = icv + 1.0f;

#pragma unroll
    for (int rep = 0; rep < 2; ++rep) {
        int idx = t + rep * 256;
        f4v v = __builtin_nontemporal_load(&proto4[base + idx]);
        f4v uu = updv[idx & 31];
        v = m * v + om * uu;
        __builtin_nontemporal_store(v, &out4[base + idx]);
    }
}

// ---------------- stage-1 column sum over B ----------------
__global__ void k_colsum(const float* __restrict__ upd, float* __restrict__ part) {
    int blk = blockIdx.x;
    int t = threadIdx.x;
    int d = t & 127;
    int h = t >> 7;

    const int rows = NB / NRED;          // 64
    int r0 = blk * rows;

    float s = 0.f;
    for (int r = r0 + h; r < r0 + rows; r += 2)
        s += upd[(size_t)r * ND + d];

    __shared__ float red[2][ND];
    red[h][d] = s;
    __syncthreads();
    if (h == 0)
        part[(size_t)blk * ND + d] = red[0][d] + red[1][d];
}

// ---------------- stage-2: mean, normalize, blend shared ----------------
__global__ void k_shared_final(const float* __restrict__ part,
                               const float* __restrict__ shared_in,
                               float* __restrict__ shared_out) {
    int d = threadIdx.x;   // 0..127

    float tot = 0.f;
#pragma unroll
    for (int j = 0; j < NRED; ++j) tot += part[(size_t)j * ND + d];
    float mean = tot / (float)NB;

    __shared__ float red[ND];
    red[d] = mean * mean;
    __syncthreads();
    for (int off = 64; off > 0; off >>= 1) {
        if (d < off) red[d] += red[d + off];
        __syncthreads();
    }
    float inv = 1.0f / fmaxf(sqrtf(red[0]), 1e-12f);
    float su = mean * inv;

#pragma unroll
    for (int p = 0; p < NP; ++p)
        shared_out[p * ND + d] = 0.9f * shared_in[p * ND + d] + 0.1f * su;
}

extern "C" void kernel_launch(void* const* d_in, const int* in_sizes, int n_in,
                              void* d_out, int out_size, void* d_ws, size_t ws_size,
                              hipStream_t stream) {
    const float* user_prototypes   = (const float*)d_in[0];  // [NU, NP, ND]
    const float* shared_prototypes = (const float*)d_in[1];  // [1, NP, ND]
    const float* interaction_count = (const float*)d_in[2];  // [NU]
    const float* features          = (const float*)d_in[3];  // [NB, NS, ND]
    const float* success_mask      = (const float*)d_in[4];  // [NB, NS]
    const int*   user_idx          = (const int*)d_in[5];    // [NB]

    float* out_proto  = (float*)d_out;                         // NU*NP*ND
    float* out_shared = out_proto + (size_t)NU * NP * ND;      // NP*ND
    float* out_ic     = out_shared + NP * ND;                  // NU

    // workspace layout (16B aligned chunks)
    int*   map  = (int*)d_ws;                                  // NU ints (200 KB)
    float* upd  = (float*)((char*)d_ws + 200704);              // NB*ND floats (4 MB)
    float* part = upd + (size_t)NB * ND;                       // NRED*ND floats (64 KB)

    k_scatter_map<<<(NB + 255) / 256, 256, 0, stream>>>(user_idx, map);

    k_big<<<NU, 256, 0, stream>>>(user_prototypes, interaction_count,
                                  features, success_mask, map, user_idx,
                                  out_proto, out_ic, upd);

    k_colsum<<<NRED, 256, 0, stream>>>(upd, part);
    k_shared_final<<<1, ND, 0, stream>>>(part, shared_prototypes, out_shared);
}